// Round 1
// baseline (3248.955 us; speedup 1.0000x reference)
//
#include <hip/hip_runtime.h>
#include <cstdint>
#include <cstddef>

#define B 128
#define T 64
#define IDIM 128
#define E 256
#define H 512

__device__ __forceinline__ float waveReduceSum(float v) {
    for (int off = 32; off > 0; off >>= 1) v += __shfl_xor(v, off, 64);
    return v;
}

__device__ __forceinline__ float sigmoidf_(float x) {
    return 1.0f / (1.0f + __expf(-x));
}

// ---------------------------------------------------------------------------
// x[b,t,i] = dot(input[b,t,i,:], news_W) + news_b   (HBM-bound, 1 GB read)
// one wave per output, 4 waves per block
__global__ __launch_bounds__(256) void news_kernel(
    const float* __restrict__ in, const float* __restrict__ nW,
    const float* __restrict__ nb, float* __restrict__ x)
{
    int out_idx = blockIdx.x * 4 + (threadIdx.x >> 6);
    int lane = threadIdx.x & 63;
    const float4* src = (const float4*)(in + (size_t)out_idx * E);
    float4 a = src[lane];
    float4 wv = ((const float4*)nW)[lane];
    float s = a.x * wv.x + a.y * wv.y + a.z * wv.z + a.w * wv.w;
    s = waveReduceSum(s);
    if (lane == 0) x[out_idx] = s + nb[0];
}

// ---------------------------------------------------------------------------
// z2[b,i,s] = sum_t x[b,t,i] * A2[s,t] + b2[s]   layout [B,I,T]
// one 64-thread block per (b,i)
__global__ __launch_bounds__(64) void z2_kernel(
    const float* __restrict__ x, const float* __restrict__ A2,
    const float* __restrict__ b2, float* __restrict__ z2)
{
    int b = blockIdx.x >> 7;
    int i = blockIdx.x & 127;
    int s = threadIdx.x;
    __shared__ float xs[T];
    xs[s] = x[((size_t)b * T + s) * IDIM + i];
    __syncthreads();
    float acc = b2[s];
    const float* arow = A2 + s * T;
#pragma unroll 8
    for (int tt = 0; tt < T; ++tt) acc += xs[tt] * arow[tt];
    z2[((size_t)b * IDIM + i) * T + s] = acc;
}

// ---------------------------------------------------------------------------
// WT[k][j]: k in [0,640), j in [0,2048). k<128 -> W_ih[j][k], else W_hh[j][k-128]
__global__ __launch_bounds__(256) void wt_kernel(
    const float* __restrict__ Wih, const float* __restrict__ Whh,
    float* __restrict__ WT)
{
    int idx = blockIdx.x * 256 + threadIdx.x;
    if (idx >= 640 * 2048) return;
    int k = idx >> 11, j = idx & 2047;
    WT[idx] = (k < 128) ? Wih[j * 128 + k] : Whh[j * 512 + (k - 128)];
}

// ---------------------------------------------------------------------------
// Per step t: attention. One block per batch element b. 256 threads (4 waves).
// z1[t'] = dot(hc, A1[t',:]) + b1[t']         (hc = [h;c], 1024)
// z3[i]  = sum_t tanh(z1[t]+z2[b,i,t])*a3[t]  (a3 bias dropped: softmax-invariant)
// attn   = softmax_i(z3);  w[b,i] = attn[i]*x[b,t,i]
__global__ __launch_bounds__(256) void attn_kernel(
    const float* __restrict__ h, const float* __restrict__ c,
    const float* __restrict__ A1, const float* __restrict__ b1,
    const float* __restrict__ z2, const float* __restrict__ a3w,
    const float* __restrict__ x, int t, float* __restrict__ w)
{
    int b = blockIdx.x;
    int tid = threadIdx.x;
    int lane = tid & 63, wid = tid >> 6;
    __shared__ float hc[2 * H];
    __shared__ float z1s[T];
    __shared__ float red[IDIM];
    for (int k = tid; k < H; k += 256) {
        hc[k]     = h[b * H + k];
        hc[H + k] = c[b * H + k];
    }
    __syncthreads();
    const float4* hc4 = (const float4*)hc;  // 256 float4
    // z1: wave `wid` handles rows tt = r*4 + wid
    for (int r = 0; r < 16; ++r) {
        int tt = r * 4 + wid;
        const float4* row = (const float4*)(A1 + (size_t)tt * (2 * H));
        float p = 0.f;
#pragma unroll
        for (int q = 0; q < 4; ++q) {
            float4 av = row[q * 64 + lane];
            float4 hv = hc4[q * 64 + lane];
            p += av.x * hv.x + av.y * hv.y + av.z * hv.z + av.w * hv.w;
        }
        p = waveReduceSum(p);
        if (lane == 0) z1s[tt] = p + b1[tt];
    }
    __syncthreads();
    // z3: thread pair per i
    int i = tid >> 1, half = tid & 1;
    const float* z2row = z2 + ((size_t)b * IDIM + i) * T + half * 32;
    const float* z1p = z1s + half * 32;
    const float* a3p = a3w + half * 32;
    float acc = 0.f;
#pragma unroll 8
    for (int tt = 0; tt < 32; ++tt)
        acc += tanhf(z1p[tt] + z2row[tt]) * a3p[tt];
    acc += __shfl_xor(acc, 1, 64);
    if (!half) red[i] = acc;
    __syncthreads();
    // softmax over 128 entries + weight by x_t, wave 0 only
    if (wid == 0) {
        float v0 = red[lane], v1 = red[lane + 64];
        float m = fmaxf(v0, v1);
        for (int off = 32; off > 0; off >>= 1) m = fmaxf(m, __shfl_xor(m, off, 64));
        float e0 = __expf(v0 - m), e1 = __expf(v1 - m);
        float ssum = waveReduceSum(e0 + e1);
        float inv = 1.0f / ssum;
        const float* xt = x + ((size_t)b * T + t) * IDIM;
        w[b * IDIM + lane]      = e0 * inv * xt[lane];
        w[b * IDIM + lane + 64] = e1 * inv * xt[lane + 64];
    }
}

// ---------------------------------------------------------------------------
// Per step t: gates + LSTM update.
// grid = nb(8) x bb(32); block 256 = 4 waves; wave g handles gate g, b-tile 4.
// gates[b, g*512 + nb*64 + lane] = sum_k A[b][k] * WT[k][j] + bias
// A[b] = [w(128) ; h(512)]
__global__ __launch_bounds__(256) void gates_kernel(
    const float* __restrict__ WT, const float* __restrict__ wat,
    const float* __restrict__ hv, const float* __restrict__ cv,
    const float* __restrict__ bih, const float* __restrict__ bhh,
    int t, float* __restrict__ hn, float* __restrict__ cn,
    float* __restrict__ out)
{
    int nb = blockIdx.x & 7, bb = blockIdx.x >> 3;
    int tid = threadIdx.x, lane = tid & 63, g = tid >> 6;
    int j = g * 512 + nb * 64 + lane;
    __shared__ float A[640][4];       // [k][b_local], float4-readable per k
    __shared__ float gacc[4][4][64];  // [gate][b_local][n_local]
    for (int idx = tid; idx < 4 * 640; idx += 256) {
        int k = idx >> 2, bl = idx & 3;
        int bglob = bb * 4 + bl;
        A[k][bl] = (k < 128) ? wat[bglob * 128 + k]
                             : hv[bglob * 512 + (k - 128)];
    }
    __syncthreads();
    float acc0 = 0.f, acc1 = 0.f, acc2 = 0.f, acc3 = 0.f;
    const float* wp = WT + j;
#pragma unroll 4
    for (int k = 0; k < 640; ++k) {
        float wvv = wp[(size_t)k * 2048];
        float4 av = *((const float4*)&A[k][0]);
        acc0 += av.x * wvv;
        acc1 += av.y * wvv;
        acc2 += av.z * wvv;
        acc3 += av.w * wvv;
    }
    float bias = bih[j] + bhh[j];
    gacc[g][0][lane] = acc0 + bias;
    gacc[g][1][lane] = acc1 + bias;
    gacc[g][2][lane] = acc2 + bias;
    gacc[g][3][lane] = acc3 + bias;
    __syncthreads();
    // update: thread -> (b_local = g, n_local = lane)
    int bglob = bb * 4 + g;
    int n = nb * 64 + lane;
    float ig = gacc[0][g][lane];
    float fg = gacc[1][g][lane];
    float gg = gacc[2][g][lane];
    float og = gacc[3][g][lane];
    float cold = cv[bglob * 512 + n];
    float cnew = sigmoidf_(fg) * cold + sigmoidf_(ig) * tanhf(gg);
    float hnew = sigmoidf_(og) * tanhf(cnew);
    cn[bglob * 512 + n] = cnew;
    hn[bglob * 512 + n] = hnew;
    out[((size_t)bglob * T + t) * H + n] = hnew;
}

// ---------------------------------------------------------------------------
extern "C" void kernel_launch(void* const* d_in, const int* in_sizes, int n_in,
                              void* d_out, int out_size, void* d_ws, size_t ws_size,
                              hipStream_t stream)
{
    const float* input  = (const float*)d_in[0];
    const float* news_W = (const float*)d_in[1];
    const float* news_b = (const float*)d_in[2];
    const float* A1     = (const float*)d_in[3];
    const float* b1     = (const float*)d_in[4];
    const float* A2     = (const float*)d_in[5];
    const float* b2     = (const float*)d_in[6];
    const float* a3w    = (const float*)d_in[7];
    // d_in[8] = attn3_b: softmax-invariant, unused
    const float* Wih    = (const float*)d_in[9];
    const float* Whh    = (const float*)d_in[10];
    const float* bih    = (const float*)d_in[11];
    const float* bhh    = (const float*)d_in[12];
    float* out = (float*)d_out;

    char* ws = (char*)d_ws;
    size_t off = 0;
    auto alloc = [&](size_t nelem) {
        float* p = (float*)(ws + off);
        off += ((nelem * 4 + 255) / 256) * 256;
        return p;
    };
    float* x   = alloc((size_t)B * T * IDIM);      // 4 MB
    float* z2  = alloc((size_t)B * IDIM * T);      // 4 MB
    float* WT  = alloc((size_t)640 * 2048);        // 5 MB
    float* wat = alloc((size_t)B * IDIM);          // 64 KB
    float* h0  = alloc((size_t)B * H);             // ping-pong h/c
    float* c0  = alloc((size_t)B * H);
    float* h1  = alloc((size_t)B * H);
    float* c1  = alloc((size_t)B * H);

    // zero initial h,c (h0,c0 are adjacent, each B*H*4 bytes, 256-aligned)
    hipMemsetAsync(h0, 0, (size_t)B * H * 4 * 2, stream);

    news_kernel<<<B * T * IDIM / 4, 256, 0, stream>>>(input, news_W, news_b, x);
    z2_kernel<<<B * IDIM, 64, 0, stream>>>(x, A2, b2, z2);
    wt_kernel<<<(640 * 2048 + 255) / 256, 256, 0, stream>>>(Wih, Whh, WT);

    float* hbuf[2] = {h0, h1};
    float* cbuf[2] = {c0, c1};
    for (int t = 0; t < T; ++t) {
        int cur = t & 1, nxt = cur ^ 1;
        attn_kernel<<<B, 256, 0, stream>>>(hbuf[cur], cbuf[cur], A1, b1, z2,
                                           a3w, x, t, wat);
        gates_kernel<<<256, 256, 0, stream>>>(WT, wat, hbuf[cur], cbuf[cur],
                                              bih, bhh, t, hbuf[nxt], cbuf[nxt],
                                              out);
    }
}